// Round 10
// baseline (38.440 us; speedup 1.0000x reference)
//
#include <hip/hip_runtime.h>

#define IN_F   4096
#define OUT_F  4096
#define BATCH  512
#define NCONN  64
#define BT     4       // batch rows per block
#define OGRP   1024    // output features per block (1 per thread)
#define NTHR   1024

typedef unsigned short u16;
typedef u16 us4 __attribute__((ext_vector_type(4)));        // 4 packed k-indices, 8 B
typedef _Float16 h4v __attribute__((ext_vector_type(4)));   // 8 B LDS granule

static __device__ __forceinline__ h4v h4_max(h4v a, h4v b) {
    h4v r;
#pragma unroll
    for (int i = 0; i < 4; ++i) r[i] = a[i] > b[i] ? a[i] : b[i];
    return r;
}
static __device__ __forceinline__ h4v h4_min(h4v a, h4v b) {
    h4v r;
#pragma unroll
    for (int i = 0; i < 4; ++i) r[i] = a[i] < b[i] ? a[i] : b[i];
    return r;
}

// ---------------- Kernel 1: pack conn -> connP[kb][o] = ushort4 of k=4kb..4kb+3 ----
__global__ __launch_bounds__(256) void pack_kernel(const int* __restrict__ conn,
                                                   us4* __restrict__ connP) {
    __shared__ u16 tile[64][68];               // [o_local][k]
    const int o0 = blockIdx.x * 64;
    const int t  = threadIdx.x;
    const int ol = t >> 2;                     // 0..63
    const int4* __restrict__ c4 = reinterpret_cast<const int4*>(conn);
#pragma unroll
    for (int i = 0; i < 4; ++i) {
        const int4 v = c4[(size_t)(o0 + ol) * 16 + (t & 3) * 4 + i];
        const int kbase = (t & 3) * 16 + i * 4;
        tile[ol][kbase + 0] = (u16)v.x;
        tile[ol][kbase + 1] = (u16)v.y;
        tile[ol][kbase + 2] = (u16)v.z;
        tile[ol][kbase + 3] = (u16)v.w;
    }
    __syncthreads();
    const int o  = o0 + (t & 63);
    const int k0 = (t >> 6) * 4;               // 0,4,8,12
#pragma unroll
    for (int i = 0; i < 4; ++i) {
        const int kb = k0 + i;
        us4 p;
        p[0] = tile[t & 63][4 * kb + 0];
        p[1] = tile[t & 63][4 * kb + 1];
        p[2] = tile[t & 63][4 * kb + 2];
        p[3] = tile[t & 63][4 * kb + 3];
        connP[(size_t)kb * OUT_F + o] = p;     // coalesced 8 B stores
    }
}

// ---------------- Kernel 2: LDS-staged gather + reduce ----------------
// Block: 4 batch rows x 1024 o's. x-slice fp16 in 32 KB LDS. 2 blocks/CU,
// 32 waves/CU.
__global__ __launch_bounds__(NTHR, 8) void agg_kernel(const float* __restrict__ x,
                                                      const us4* __restrict__ connP,
                                                      const int* __restrict__ opidx,
                                                      float* __restrict__ out) {
    __shared__ alignas(16) _Float16 xs[IN_F * BT];   // [j][b], 32 KB

    const int bid   = blockIdx.x;
    const int btile = (bid & 7) * 16 + (bid >> 5);   // 0..127 (XCD-affine)
    const int og    = (bid >> 3) & 3;                // 0..3
    const int o0    = og * OGRP;
    const int b0    = btile * BT;
    const int t     = threadIdx.x;

    // ---- stage x slice -> LDS fp16 [j][b] ----
    const int bb   = t & 3;
    const int joff = t >> 2;                         // 0..255
    const float* __restrict__ xrow = x + (size_t)(b0 + bb) * IN_F;
#pragma unroll 4
    for (int it = 0; it < 16; ++it) {
        const int j = it * 256 + joff;
        xs[j * BT + bb] = (_Float16)xrow[j];
    }
    __syncthreads();

    // ---- gather + reduce: one o per thread ----
    const int o = o0 + t;
    const us4* __restrict__ cp = connP + o;

    us4 i0 = cp[0];
    us4 i1 = cp[OUT_F];
    us4 i2 = cp[2 * (size_t)OUT_F];
    us4 i3 = cp[3 * (size_t)OUT_F];

    float s0 = 0.f, s1 = 0.f, s2 = 0.f, s3 = 0.f;
    const _Float16 HNEG = __builtin_bit_cast(_Float16, (u16)0xFC00);  // -inf
    const _Float16 HPOS = __builtin_bit_cast(_Float16, (u16)0x7C00);  // +inf
    h4v hx = {HNEG, HNEG, HNEG, HNEG};
    h4v hn = {HPOS, HPOS, HPOS, HPOS};

    const h4v* __restrict__ xs4 = reinterpret_cast<const h4v*>(xs);

    for (int kb = 0; kb < 16; kb += 2) {
        h4v g[8];
        g[0] = xs4[i0[0]];  g[1] = xs4[i0[1]];
        g[2] = xs4[i0[2]];  g[3] = xs4[i0[3]];
        g[4] = xs4[i1[0]];  g[5] = xs4[i1[1]];
        g[6] = xs4[i1[2]];  g[7] = xs4[i1[3]];

        us4 inA = i2, inB = i3;
        if (kb < 12) {
            inA = cp[(size_t)(kb + 4) * OUT_F];
            inB = cp[(size_t)(kb + 5) * OUT_F];
        }

#pragma unroll
        for (int q = 0; q < 8; ++q) {
            hx = h4_max(hx, g[q]);
            hn = h4_min(hn, g[q]);
            s0 += (float)g[q][0];
            s1 += (float)g[q][1];
            s2 += (float)g[q][2];
            s3 += (float)g[q][3];
        }
        i0 = i2; i1 = i3; i2 = inA; i3 = inB;
    }

    const float sv[4] = {s0, s1, s2, s3};
    const float xv[4] = {(float)hx[0], (float)hx[1], (float)hx[2], (float)hx[3]};
    const float nv[4] = {(float)hn[0], (float)hn[1], (float)hn[2], (float)hn[3]};

    // ---- epilogue: scalar NT stores, coalesced along o ----
    const int op = opidx[o];
    float* __restrict__ fwd  = out;                          // (B, OUT_F)
    float* __restrict__ outp = out + (size_t)BATCH * OUT_F;  // (B, 4, OUT_F)

#pragma unroll
    for (int i = 0; i < 4; ++i) {
        const float ss = sv[i];
        const float mm = ss * 0.015625f;
        const float hxv = xv[i];
        const float lnv = nv[i];
        const float fw = (op == 0) ? mm : (op == 1) ? ss : (op == 2) ? hxv : lnv;
        const size_t rowO = (size_t)(b0 + i) * (4 * OUT_F) + o;
        __builtin_nontemporal_store(fw, fwd + (size_t)(b0 + i) * OUT_F + o);
        __builtin_nontemporal_store(mm, outp + rowO);
        __builtin_nontemporal_store(ss, outp + rowO + OUT_F);
        __builtin_nontemporal_store(hxv, outp + rowO + 2 * OUT_F);
        __builtin_nontemporal_store(lnv, outp + rowO + 3 * OUT_F);
    }
}

extern "C" void kernel_launch(void* const* d_in, const int* in_sizes, int n_in,
                              void* d_out, int out_size, void* d_ws, size_t ws_size,
                              hipStream_t stream) {
    const float* x     = (const float*)d_in[0];
    const int*   conn  = (const int*)d_in[1];
    const int*   opidx = (const int*)d_in[2];
    float*       out   = (float*)d_out;
    us4*         connP = (us4*)d_ws;    // 16 x 4096 x 8 B = 512 KiB

    pack_kernel<<<OUT_F / 64, 256, 0, stream>>>(conn, connP);

    const int nblocks = (BATCH / BT) * (OUT_F / OGRP);   // 128 * 4 = 512
    agg_kernel<<<nblocks, NTHR, 0, stream>>>(x, connP, opidx, out);
}

// Round 11
// 38.385 us; speedup vs baseline: 1.0014x; 1.0014x over previous
//
#include <hip/hip_runtime.h>

#define IN_F   4096
#define OUT_F  4096
#define BATCH  512
#define NCONN  64
#define BT     8       // batch rows per block (16 B fp16 granule -> ds_read_b128)
#define OGRP   512     // output features per block (1 per thread)
#define NTHR   512

typedef _Float16 h8 __attribute__((ext_vector_type(8)));   // 16 B LDS granule

// ---------------- Kernel 1: connT[k][o] = conn[o][k] ----------------
__global__ __launch_bounds__(256) void connT_kernel(const int* __restrict__ conn,
                                                    int* __restrict__ connT) {
    __shared__ int tile[64][65];
    const int o0 = blockIdx.x * 64;
    const int tx = threadIdx.x & 63;
    const int ty = threadIdx.x >> 6;   // 0..3
#pragma unroll
    for (int r = 0; r < 16; ++r) {
        const int row = ty * 16 + r;                  // o-local
        tile[row][tx] = conn[(size_t)(o0 + row) * NCONN + tx];
    }
    __syncthreads();
#pragma unroll
    for (int r = 0; r < 16; ++r) {
        const int k = ty * 16 + r;
        connT[(size_t)k * OUT_F + o0 + tx] = tile[tx][k];
    }
}

// ---------------- Kernel 2: LDS-staged gather + reduce ----------------
// Block: 8 batch rows x 512 o's. x-slice (4096 j x 8 b) fp16 in 64 KB LDS.
// 512 blocks -> 2 blocks/CU (128 KB LDS), 16 waves/CU.
__global__ __launch_bounds__(NTHR, 4) void agg_kernel(const float* __restrict__ x,
                                                      const int* __restrict__ connT,
                                                      const int* __restrict__ opidx,
                                                      float* __restrict__ out) {
    __shared__ alignas(16) _Float16 xs[IN_F * BT];   // [j][b], 64 KB

    // 512 blocks = 64 b-tiles x 8 o-groups. bid&7 = XCD (HW round-robin);
    // all 8 o-group blocks of one b-tile group land on one XCD -> staging
    // reads of those x rows are L2-resident (8 rows x 16 KB x 8 btiles = 1 MB).
    const int bid   = blockIdx.x;
    const int btile = (bid & 7) * 8 + (bid >> 6);    // 0..63
    const int og    = (bid >> 3) & 7;                // 0..7
    const int o0    = og * OGRP;
    const int b0    = btile * BT;
    const int t     = threadIdx.x;

    // ---- stage x slice -> LDS fp16 [j][b] ----
    // lane l: b = l&7, j = base + (l>>3): ds_write_b16 addr = 16j+2b ->
    // 8 lanes share 4 banks pairwise (2-way = free), wave spans 32 banks.
    const int bb   = t & 7;
    const int joff = t >> 3;                         // 0..63
    const float* __restrict__ xrow = x + (size_t)(b0 + bb) * IN_F;
#pragma unroll 8
    for (int it = 0; it < 64; ++it) {
        const int j = it * 64 + joff;
        xs[j * BT + bb] = (_Float16)xrow[j];
    }
    __syncthreads();

    // ---- gather + reduce: one o per thread, 8-deep pipeline ----
    const int o = o0 + t;
    const int* __restrict__ cp = connT + o;
    const h8* __restrict__ xs8 = reinterpret_cast<const h8*>(xs);

    float s[8];
#pragma unroll
    for (int i = 0; i < 8; ++i) s[i] = 0.f;
    const _Float16 HNEG = __builtin_bit_cast(_Float16, (unsigned short)0xFC00);
    const _Float16 HPOS = __builtin_bit_cast(_Float16, (unsigned short)0x7C00);
    h8 hx = {HNEG, HNEG, HNEG, HNEG, HNEG, HNEG, HNEG, HNEG};
    h8 hn = {HPOS, HPOS, HPOS, HPOS, HPOS, HPOS, HPOS, HPOS};

    int idx[8];
#pragma unroll
    for (int q = 0; q < 8; ++q) idx[q] = cp[(size_t)q * OUT_F];

    for (int kb = 0; kb < NCONN; kb += 8) {
        h8 g[8];
#pragma unroll
        for (int q = 0; q < 8; ++q)
            g[q] = xs8[idx[q]];                      // ds_read_b128
        if (kb + 8 < NCONN) {
#pragma unroll
            for (int q = 0; q < 8; ++q) idx[q] = cp[(size_t)(kb + 8 + q) * OUT_F];
        }
#pragma unroll
        for (int q = 0; q < 8; ++q) {
            hx = __builtin_elementwise_max(hx, g[q]);   // v_pk_max_f16 x4
            hn = __builtin_elementwise_min(hn, g[q]);   // v_pk_min_f16 x4
#pragma unroll
            for (int i = 0; i < 8; ++i)
                s[i] = fmaf((float)g[q][i], 1.0f, s[i]);   // v_fma_mix candidate
        }
    }

    // ---- epilogue: scalar NT stores, coalesced along o ----
    const int op = opidx[o];
    float* __restrict__ fwd  = out;                          // (B, OUT_F)
    float* __restrict__ outp = out + (size_t)BATCH * OUT_F;  // (B, 4, OUT_F)

#pragma unroll
    for (int i = 0; i < 8; ++i) {
        const float ss = s[i];
        const float mm = ss * 0.015625f;
        const float hxv = (float)hx[i];
        const float lnv = (float)hn[i];
        const float fw = (op == 0) ? mm : (op == 1) ? ss : (op == 2) ? hxv : lnv;
        const size_t rowO = (size_t)(b0 + i) * (4 * OUT_F) + o;
        __builtin_nontemporal_store(fw, fwd + (size_t)(b0 + i) * OUT_F + o);
        __builtin_nontemporal_store(mm, outp + rowO);
        __builtin_nontemporal_store(ss, outp + rowO + OUT_F);
        __builtin_nontemporal_store(hxv, outp + rowO + 2 * OUT_F);
        __builtin_nontemporal_store(lnv, outp + rowO + 3 * OUT_F);
    }
}

extern "C" void kernel_launch(void* const* d_in, const int* in_sizes, int n_in,
                              void* d_out, int out_size, void* d_ws, size_t ws_size,
                              hipStream_t stream) {
    const float* x     = (const float*)d_in[0];
    const int*   conn  = (const int*)d_in[1];
    const int*   opidx = (const int*)d_in[2];
    float*       out   = (float*)d_out;
    int*         connT = (int*)d_ws;    // 64 x 4096 ints = 1 MiB

    connT_kernel<<<OUT_F / 64, 256, 0, stream>>>(conn, connT);

    const int nblocks = (BATCH / BT) * (OUT_F / OGRP);   // 64 * 8 = 512
    agg_kernel<<<nblocks, NTHR, 0, stream>>>(x, connT, opidx, out);
}